// Round 10
// baseline (148.212 us; speedup 1.0000x reference)
//
#include <hip/hip_runtime.h>
#include <math.h>

#define N_SEQ 2048
#define DM    512
#define NTOK  4096
#define NH    8
#define HD    64
#define NSLOT 15

typedef __attribute__((ext_vector_type(8))) short short8;
typedef __attribute__((ext_vector_type(4))) short short4_t;
typedef __attribute__((ext_vector_type(4))) float f32x4;
typedef __attribute__((ext_vector_type(2))) unsigned uint2_t;

__device__ inline short f2bf(float x) {
    union { float f; unsigned u; } v; v.f = x;
    unsigned r = v.u + 0x7fff + ((v.u >> 16) & 1);
    return (short)(r >> 16);
}
__device__ inline float bf2f(short s) {
    union { unsigned u; float f; } v; v.u = ((unsigned)(unsigned short)s) << 16;
    return v.f;
}
__device__ inline unsigned pkbf(float a, float b) {
    return ((unsigned)(unsigned short)f2bf(b) << 16) | (unsigned)(unsigned short)f2bf(a);
}
__device__ inline float ftanh(float x) {
    float e = __expf(2.f * x);
    return 1.f - 2.f / (e + 1.f);
}

__device__ inline f32x4 mfma16(short8 a, short8 b, f32x4 c) {
    return __builtin_amdgcn_mfma_f32_16x16x32_bf16(a, b, c, 0, 0, 0);
}

__device__ __forceinline__ void async_cp16(const short* g, short* l) {
    __builtin_amdgcn_global_load_lds(
        (const __attribute__((address_space(1))) void*)g,
        (__attribute__((address_space(3))) void*)l, 16, 0, 0);
}

// ---------------- fused: LN(x)->bf16 + lg zero-init  |  weight cvt fp32->bf16 ----
__global__ __launch_bounds__(256) void k_lncvt(
    const float* __restrict__ x, const float* __restrict__ g,
    const float* __restrict__ b, short* __restrict__ y, float* __restrict__ lg,
    const float* __restrict__ Wq, const float* __restrict__ Wk,
    const float* __restrict__ Wv, const float* __restrict__ Tw1,
    const float* __restrict__ Wo,
    short* __restrict__ wcat, short* __restrict__ wo) {
    int blk = blockIdx.x, t = threadIdx.x;
    if (blk < 2048) {
        int sub = t >> 7, tt = t & 127;
        int tk = blk * 2 + sub;
        if (tt == 0) lg[tk] = 0.f;
        float4 xv = ((const float4*)(x + (size_t)tk * DM))[tt];
        float s = xv.x + xv.y + xv.z + xv.w;
        float q = xv.x*xv.x + xv.y*xv.y + xv.z*xv.z + xv.w*xv.w;
        for (int o = 32; o; o >>= 1) { s += __shfl_down(s, o); q += __shfl_down(q, o); }
        __shared__ float ls[4], lq[4];
        if ((t & 63) == 0) { ls[t >> 6] = s; lq[t >> 6] = q; }
        __syncthreads();
        s = ls[sub * 2] + ls[sub * 2 + 1];
        q = lq[sub * 2] + lq[sub * 2 + 1];
        float mu = s * (1.f / DM);
        float var = q * (1.f / DM) - mu * mu;
        float rs = rsqrtf(var + 1e-5f);
        float4 gv = ((const float4*)g)[tt], bv = ((const float4*)b)[tt];
        short4_t o;
        o[0] = f2bf((xv.x - mu) * rs * gv.x + bv.x);
        o[1] = f2bf((xv.y - mu) * rs * gv.y + bv.y);
        o[2] = f2bf((xv.z - mu) * rs * gv.z + bv.z);
        o[3] = f2bf((xv.w - mu) * rs * gv.w + bv.w);
        *(short4_t*)&y[(size_t)tk * DM + tt * 4] = o;
    } else {
        int id = (blk - 2048) * 256 + t;
        if (id < 262144) {
            int z = id >> 16; int off = id & 65535;
            const float* s = (z == 0) ? Wq : (z == 1) ? Wk : (z == 2) ? Wv : Tw1;
            float4 v = ((const float4*)s)[off];
            short4_t o = {f2bf(v.x), f2bf(v.y), f2bf(v.z), f2bf(v.w)};
            *(short4_t*)(wcat + (size_t)z * 262144 + (size_t)off * 4) = o;
        } else {
            int off = id - 262144;
            float4 v = ((const float4*)Wo)[off];
            short4_t o = {f2bf(v.x), f2bf(v.y), f2bf(v.z), f2bf(v.w)};
            *(short4_t*)(wo + (size_t)off * 4) = o;
        }
    }
}

// ---------------- bf16 MFMA NT-GEMM (QKV + T-logit fused), BK=64 2-phase ------
// Q epilogue scale folds softmax 1/8 AND log2(e) (attn runs exp2-domain softmax).
__global__ __launch_bounds__(256) void k_gemmqkvt(
    const short* __restrict__ A, const short* __restrict__ W,
    const float* __restrict__ Tb1, const float* __restrict__ Tw2,
    short* __restrict__ qb, short* __restrict__ kb, short* __restrict__ vtb,
    short* __restrict__ vb, float* __restrict__ lg) {
    __shared__ short smem[32768];   // max(2*(8192+8192), 128*136)
    int t = threadIdx.x;
    int lane = t & 63, w = t >> 6;
    int wy = w >> 1, wx = w & 1;
    int ln = lane & 15, q4 = lane >> 4;
    int c0 = blockIdx.x * 128, m0 = blockIdx.y * 128;
    f32x4 acc[4][4];
    f32x4 zero = {0.f, 0.f, 0.f, 0.f};
    #pragma unroll
    for (int i = 0; i < 4; i++)
        #pragma unroll
        for (int j = 0; j < 4; j++) acc[i][j] = zero;
    #pragma unroll
    for (int i2 = 0; i2 < 4; i2++) {
        int id = t + 256 * i2;
        int row = id >> 3, cc = id & 7;
        int scol = (cc ^ (row & 7)) << 3;
        async_cp16(&A[(size_t)(m0 + row) * DM + scol], &smem[id * 8]);
        async_cp16(&W[(size_t)(c0 + row) * DM + scol], &smem[8192 + id * 8]);
    }
    __syncthreads();
    for (int kk = 0; kk < 8; kk++) {
        short* AsB = &smem[(kk & 1) * 16384];
        short* BsB = AsB + 8192;
        if (kk < 7) {
            short* AsN = &smem[((kk & 1) ^ 1) * 16384];
            short* BsN = AsN + 8192;
            int k0 = (kk + 1) * 64;
            #pragma unroll
            for (int i2 = 0; i2 < 4; i2++) {
                int id = t + 256 * i2;
                int row = id >> 3, cc = id & 7;
                int scol = k0 + ((cc ^ (row & 7)) << 3);
                async_cp16(&A[(size_t)(m0 + row) * DM + scol], &AsN[id * 8]);
                async_cp16(&W[(size_t)(c0 + row) * DM + scol], &BsN[id * 8]);
            }
        }
        short8 af[2][4], bfr[2][4];
        #pragma unroll
        for (int ks = 0; ks < 2; ks++) {
            int chnk = ((ks * 4 + q4) ^ (ln & 7)) << 3;
            #pragma unroll
            for (int i = 0; i < 4; i++)
                af[ks][i] = *(short8*)&AsB[(wy * 64 + i * 16 + ln) * 64 + chnk];
            #pragma unroll
            for (int j = 0; j < 4; j++)
                bfr[ks][j] = *(short8*)&BsB[(wx * 64 + j * 16 + ln) * 64 + chnk];
        }
        #pragma unroll
        for (int ks = 0; ks < 2; ks++)
            #pragma unroll
            for (int i = 0; i < 4; i++)
                #pragma unroll
                for (int j = 0; j < 4; j++)
                    acc[i][j] = mfma16(af[ks][i], bfr[ks][j], acc[i][j]);
        __syncthreads();
    }
    short* Es = smem;
    int z = c0 >> 9;
    int bi = m0 >> 11, n0 = m0 & (N_SEQ - 1);
    int hp = (c0 & 511) >> 6;
    if (z < 2) {
        short* dst0 = (z == 0) ? qb : kb;
        float sc2 = (z == 0) ? 0.18033688f : 1.0f;   // 0.125 * log2(e)
        #pragma unroll
        for (int i = 0; i < 4; i++)
            #pragma unroll
            for (int j = 0; j < 4; j++)
                #pragma unroll
                for (int r = 0; r < 4; r++) {
                    int nl = wy * 64 + i * 16 + q4 * 4 + r;
                    int cl = wx * 64 + j * 16 + ln;
                    Es[nl * 136 + cl] = f2bf(acc[i][j][r] * sc2);
                }
        __syncthreads();
        #pragma unroll
        for (int ii = 0; ii < 8; ii++) {
            int id = t + 256 * ii;
            int nl = id >> 4, c8 = id & 15;
            short8 v = *(short8*)&Es[nl * 136 + c8 * 8];
            int hh = hp + (c8 >> 3), d8 = (c8 & 7) * 8;
            *(short8*)&dst0[(((size_t)bi * NH + hh) * N_SEQ + n0 + nl) * HD + d8] = v;
        }
    } else if (z == 2) {
        if (hp >= 4) {
            #pragma unroll
            for (int i = 0; i < 4; i++)
                #pragma unroll
                for (int j = 0; j < 4; j++)
                    #pragma unroll
                    for (int r = 0; r < 4; r++) {
                        int nl = wy * 64 + i * 16 + q4 * 4 + r;
                        int cl = wx * 64 + j * 16 + ln;
                        Es[nl * 136 + cl] = f2bf(acc[i][j][r]);
                    }
            __syncthreads();
            #pragma unroll
            for (int ii = 0; ii < 8; ii++) {
                int id = t + 256 * ii;
                int nl = id >> 4, c8 = id & 15;
                int hh = hp + (c8 >> 3);
                if (hh >= 5) {
                    short8 v = *(short8*)&Es[nl * 136 + c8 * 8];
                    int d8 = (c8 & 7) * 8;
                    *(short8*)&vb[(((size_t)bi * NH + hh) * N_SEQ + n0 + nl) * HD + d8] = v;
                }
            }
            __syncthreads();
        }
        #pragma unroll
        for (int i = 0; i < 4; i++)
            #pragma unroll
            for (int j = 0; j < 4; j++) {
                int nl0 = wy * 64 + i * 16 + q4 * 4;
                int dl = wx * 64 + j * 16 + ln;
                *(unsigned*)&Es[dl * 136 + nl0]     = pkbf(acc[i][j][0], acc[i][j][1]);
                *(unsigned*)&Es[dl * 136 + nl0 + 2] = pkbf(acc[i][j][2], acc[i][j][3]);
            }
        __syncthreads();
        #pragma unroll
        for (int ii = 0; ii < 8; ii++) {
            int id = t + 256 * ii;
            int dl = id >> 4, nc = id & 15;
            short8 v = *(short8*)&Es[dl * 136 + nc * 8];
            int h = hp + (dl >> 6), d = dl & 63;
            *(short8*)&vtb[(((size_t)bi * NH + h) * HD + d) * N_SEQ + n0 + nc * 8] = v;
        }
    } else {
        #pragma unroll
        for (int i = 0; i < 4; i++) {
            #pragma unroll
            for (int r = 0; r < 4; r++) {
                float s = 0.f;
                #pragma unroll
                for (int j = 0; j < 4; j++) {
                    int tc = (c0 & 511) + wx * 64 + j * 16 + ln;
                    s += ftanh(acc[i][j][r] + Tb1[tc]) * Tw2[tc];
                }
                s += __shfl_xor(s, 1);
                s += __shfl_xor(s, 2);
                s += __shfl_xor(s, 4);
                s += __shfl_xor(s, 8);
                if (ln == 0) {
                    int row = m0 + wy * 64 + i * 16 + q4 * 4 + r;
                    atomicAdd(&lg[row], s);
                }
            }
        }
    }
}

// ---------------- proj GEMM 128x64 tiles, BK=64 2-phase: proj(bf16) = A @ Wo^T --
__global__ __launch_bounds__(256) void k_gemmp(
    const short* __restrict__ A, const short* __restrict__ W,
    short* __restrict__ projb) {
    __shared__ short smem[24576];
    int t = threadIdx.x;
    int lane = t & 63, w = t >> 6;
    int wy = w >> 1, wx = w & 1;
    int ln = lane & 15, q4 = lane >> 4;
    int c0 = blockIdx.x * 64, m0 = blockIdx.y * 128;
    f32x4 acc[4][2];
    f32x4 zero = {0.f, 0.f, 0.f, 0.f};
    #pragma unroll
    for (int i = 0; i < 4; i++) { acc[i][0] = zero; acc[i][1] = zero; }
    #pragma unroll
    for (int i2 = 0; i2 < 4; i2++) {
        int id = t + 256 * i2;
        int row = id >> 3, cc = id & 7;
        int scol = (cc ^ (row & 7)) << 3;
        async_cp16(&A[(size_t)(m0 + row) * DM + scol], &smem[id * 8]);
        if (i2 < 2)
            async_cp16(&W[(size_t)(c0 + row) * DM + scol], &smem[8192 + id * 8]);
    }
    __syncthreads();
    for (int kk = 0; kk < 8; kk++) {
        short* AsB = &smem[(kk & 1) * 12288];
        short* BsB = AsB + 8192;
        if (kk < 7) {
            short* AsN = &smem[((kk & 1) ^ 1) * 12288];
            short* BsN = AsN + 8192;
            int k0 = (kk + 1) * 64;
            #pragma unroll
            for (int i2 = 0; i2 < 4; i2++) {
                int id = t + 256 * i2;
                int row = id >> 3, cc = id & 7;
                int scol = k0 + ((cc ^ (row & 7)) << 3);
                async_cp16(&A[(size_t)(m0 + row) * DM + scol], &AsN[id * 8]);
                if (i2 < 2)
                    async_cp16(&W[(size_t)(c0 + row) * DM + scol], &BsN[id * 8]);
            }
        }
        short8 af[2][4], bfr[2][2];
        #pragma unroll
        for (int ks = 0; ks < 2; ks++) {
            int chnk = ((ks * 4 + q4) ^ (ln & 7)) << 3;
            #pragma unroll
            for (int i = 0; i < 4; i++)
                af[ks][i] = *(short8*)&AsB[(wy * 64 + i * 16 + ln) * 64 + chnk];
            #pragma unroll
            for (int j = 0; j < 2; j++)
                bfr[ks][j] = *(short8*)&BsB[(wx * 32 + j * 16 + ln) * 64 + chnk];
        }
        #pragma unroll
        for (int ks = 0; ks < 2; ks++)
            #pragma unroll
            for (int i = 0; i < 4; i++)
                #pragma unroll
                for (int j = 0; j < 2; j++)
                    acc[i][j] = mfma16(af[ks][i], bfr[ks][j], acc[i][j]);
        __syncthreads();
    }
    short* Es = smem;
    #pragma unroll
    for (int i = 0; i < 4; i++)
        #pragma unroll
        for (int j = 0; j < 2; j++)
            #pragma unroll
            for (int r = 0; r < 4; r++) {
                int nl = wy * 64 + i * 16 + q4 * 4 + r;
                int cl = wx * 32 + j * 16 + ln;
                Es[nl * 72 + cl] = f2bf(acc[i][j][r]);
            }
    __syncthreads();
    #pragma unroll
    for (int ii = 0; ii < 4; ii++) {
        int id = t + 256 * ii;
        int nl = id >> 3, c8 = id & 7;
        short8 v = *(short8*)&Es[nl * 72 + c8 * 8];
        *(short8*)&projb[(size_t)(m0 + nl) * DM + c0 + c8 * 8] = v;
    }
}

// ---------------- split-K MFMA flash attention, 128-key tiles ----------------
// exp2-domain online softmax (Q pre-scaled by 0.125*log2e). P_ml m-values are
// in log2 domain; k_combine rescales with exp2f.
__global__ __launch_bounds__(256) void k_attn(const short* __restrict__ qb,
                                              const short* __restrict__ kb,
                                              const short* __restrict__ vtb,
                                              const short* __restrict__ vb,
                                              short* __restrict__ P_O,
                                              float* __restrict__ P_ml,
                                              short* __restrict__ ob,
                                              const float* __restrict__ lg,
                                              float* __restrict__ gate) {
    __shared__ short Ks[128 * 64];      // linear [key][d], content chunk-swizzled
    __shared__ short Vt[64 * 128];      // [d][key] swizzled; dilated: first V-row staging [128][64]
    __shared__ short Pa[4][16 * 136];   // per-wave [qrow][key] pad136
    __shared__ float rg[8];
    int t = threadIdx.x;
    int lane = t & 63, w = t >> 6;
    int ln = lane & 15, q4 = lane >> 4;
    int slot = blockIdx.x, qt = blockIdx.y, bi = blockIdx.z;
    int h, c;
    if (slot < 4)        { h = 0; c = slot; }
    else if (slot < 8)   { h = 1; c = slot - 4; }
    else if (slot == 8)  { h = 2; c = 0; }
    else if (slot == 9)  { h = 3; c = 0; }
    else if (slot < 12)  { h = 4; c = slot - 10; }
    else                 { h = slot - 7; c = 0; }      // 12,13,14 -> h5,h6,h7
    int solo = (slot == 8) | (slot == 9) | (slot >= 12);
    int kind = (h < 2) ? 0 : (h < 5) ? 1 : 2;
    int wnd = (h == 2 || h >= 5) ? 64 : (h == 3) ? 128 : 256;
    int dsh = (h >= 5) ? (h - 4) : 0;                  // dilation shift: h5->1 h6->2 h7->3
    int ktLo, ktHi, q0m, rres = 0;
    if (kind == 0) {
        q0m = qt * 64; ktLo = c * 4; ktHi = ktLo + 3;
    } else if (kind == 1) {
        q0m = qt * 64;
        int tLoU = (q0m - wnd) >> 7, tHiU = (q0m + 63 + wnd) >> 7;
        ktLo = tLoU + c * 3; ktHi = ktLo + 2;
        if (ktHi > tHiU) ktHi = tHiU;
        if (ktHi > 15) ktHi = 15;
        if (ktLo < 0) ktLo = 0;
    } else {
        int nct = 32 >> dsh;                 // query tiles per residue
        rres = qt >> (5 - dsh);              // residue class
        q0m = (qt & (nct - 1)) * 64;         // compressed query base
        int Lt = 16 >> dsh;                  // compressed key tiles
        ktLo = (q0m - 64) >> 7; if (ktLo < 0) ktLo = 0;
        ktHi = (q0m + 127) >> 7; if (ktHi > Lt - 1) ktHi = Lt - 1;
    }
    int p4 = (bi * 32 + qt) * NSLOT + slot;
    float* ml = P_ml + (size_t)p4 * 128;
    if (ktLo > ktHi) {
        if (t < 64) { ml[t] = -1e30f; ml[64 + t] = 0.f; }
        return;
    }
    const size_t base = ((size_t)bi * NH + h) * N_SEQ * HD;
    const short* Q = qb + base;
    const short* K = kb + base;
    const short* Vg = vtb + base;   // [d][n]
    const short* Vr = vb + base;    // [n][d] (dilated heads only)
    int qm = q0m + w * 16 + ln;                         // mask-space coordinate
    int qi = (kind == 2) ? (rres + (qm << dsh)) : qm;   // physical query row
    short8 qa[2];
    {
        const short* qrow = Q + (size_t)qi * HD + q4 * 8;
        qa[0] = *(const short8*)qrow;
        qa[1] = *(const short8*)(qrow + 32);
    }
    float m_i = -1e30f, l_i = 0.f;
    f32x4 OT[4];
    f32x4 zero = {0.f, 0.f, 0.f, 0.f};
    #pragma unroll
    for (int d = 0; d < 4; d++) OT[d] = zero;
    short* Paw = Pa[w];
    for (int kt = ktLo; kt <= ktHi; kt++) {
        int k0 = kt << 7;
        __syncthreads();
        if (kind != 2) {
            #pragma unroll
            for (int i2 = 0; i2 < 4; i2++) {
                int id = t + 256 * i2;
                int kr = id >> 3, ck = id & 7;
                async_cp16(&K[(size_t)(k0 + kr) * HD + ((ck ^ (kr & 7)) << 3)],
                           &Ks[id << 3]);
                int dr = id >> 4, cv = id & 15;
                async_cp16(&Vg[(size_t)dr * N_SEQ + k0 + ((cv ^ (dr & 15)) << 3)],
                           &Vt[id << 3]);
            }
        } else {
            // compressed gather: row kr -> physical key rres + (k0+kr)*d
            #pragma unroll
            for (int i2 = 0; i2 < 4; i2++) {
                int id = t + 256 * i2;
                int kr = id >> 3, ck = id & 7;
                int kn = rres + ((k0 + kr) << dsh);
                async_cp16(&K[(size_t)kn * HD + ((ck ^ (kr & 7)) << 3)],
                           &Ks[id << 3]);
                async_cp16(&Vr[(size_t)kn * HD + (ck << 3)],
                           &Vt[id << 3]);    // V rows staged linear [128][64]
            }
        }
        __syncthreads();
        // S^T = K·Q^T over 128 keys (S already in log2 domain via Q scale)
        f32x4 ST[8];
        #pragma unroll
        for (int nt = 0; nt < 8; nt++) ST[nt] = zero;
        __builtin_amdgcn_s_setprio(1);
        #pragma unroll
        for (int nt = 0; nt < 8; nt++) {
            #pragma unroll
            for (int ks = 0; ks < 2; ks++) {
                int cc = ((ks * 4 + q4) ^ (ln & 7)) << 3;
                short8 af = *(short8*)&Ks[(nt * 16 + ln) * 64 + cc];
                ST[nt] = mfma16(af, qa[ks], ST[nt]);
            }
        }
        __builtin_amdgcn_s_setprio(0);
        if (kind != 0) {
            // window mask in (compressed or plain) coordinates
            #pragma unroll
            for (int nt = 0; nt < 8; nt++)
                #pragma unroll
                for (int r = 0; r < 4; r++) {
                    int key = k0 + nt * 16 + q4 * 4 + r;
                    int dlt = qm - key; dlt = (dlt < 0) ? -dlt : dlt;
                    if (dlt > wnd) ST[nt][r] = -1e30f;
                }
        }
        float rm = -1e30f;
        #pragma unroll
        for (int nt = 0; nt < 8; nt++) {
            float a = fmaxf(ST[nt][0], ST[nt][1]);
            float b = fmaxf(ST[nt][2], ST[nt][3]);
            rm = fmaxf(rm, fmaxf(a, b));
        }
        rm = fmaxf(rm, __shfl_xor(rm, 16));
        rm = fmaxf(rm, __shfl_xor(rm, 32));
        float mn = fmaxf(m_i, rm);
        float sc = exp2f(m_i - mn);
        float rs = 0.f;
        #pragma unroll
        for (int nt = 0; nt < 8; nt++) {
            float p0 = exp2f(ST[nt][0] - mn);
            float p1 = exp2f(ST[nt][1] - mn);
            float p2 = exp2f(ST[nt][2] - mn);
            float p3 = exp2f(ST[nt][3] - mn);
            rs += (p0 + p1) + (p2 + p3);
            uint2_t pw = {pkbf(p0, p1), pkbf(p2, p3)};
            *(uint2_t*)&Paw[ln * 136 + nt * 16 + q4 * 4] = pw;
        }
        rs += __shfl_xor(rs, 16);
        rs += __shfl_xor(rs, 32);
        l_i = l_i * sc + rs;
        m_i = mn;
        #pragma unroll
        for (int d = 0; d < 4; d++) OT[d] *= sc;
        if (kind == 2) {
            // in-place LDS transpose: Vrow[128][64] -> Vt[64][128] (swizzled)
            int dr = t & 63, cb = t >> 6;
            short8 tv[4];
            #pragma unroll
            for (int e = 0; e < 4; e++) {
                int c8 = cb + e * 4;
                #pragma unroll
                for (int j = 0; j < 8; j++)
                    tv[e][j] = Vt[(c8 * 8 + j) * 64 + dr];
            }
            __syncthreads();
            #pragma unroll
            for (int e = 0; e < 4; e++) {
                int c8 = cb + e * 4;
                *(short8*)&Vt[dr * 128 + ((c8 ^ (dr & 15)) << 3)] = tv[e];
            }
            __syncthreads();
        }
        // O^T += V^T · P^T
        short8 pb[4];
        #pragma unroll
        for (int ks = 0; ks < 4; ks++)
            pb[ks] = *(short8*)&Paw[ln * 136 + ks * 32 + q4 * 8];
        __builtin_amdgcn_s_setprio(1);
        #pragma unroll
        for (int dt = 0; dt < 4; dt++) {
            #pragma unroll
            for (int ks = 0; ks < 4; ks++) {
                int cc = ((ks * 4 + q4) ^ ln) << 3;
                short8 a = *(short8*)&Vt[(dt * 16 + ln) * 128 + cc];
                OT[dt] = mfma16(a, pb[ks], OT[dt]);
            }
        }
        __builtin_amdgcn_s_setprio(0);
    }
    if (solo) {
        float inv = 1.f / l_i;
        #pragma unroll
        for (int dt = 0; dt < 4; dt++) {
            uint2_t ow = {pkbf(OT[dt][0] * inv, OT[dt][1] * inv),
                          pkbf(OT[dt][2] * inv, OT[dt][3] * inv)};
            *(uint2_t*)&Paw[ln * 136 + dt * 16 + q4 * 4] = ow;
        }
        short8 o0 = *(short8*)&Paw[ln * 136 + q4 * 16];
        short8 o1 = *(short8*)&Paw[ln * 136 + q4 * 16 + 8];
        short* dst = ob + ((size_t)bi * N_SEQ + qi) * DM + h * 64 + q4 * 16;
        *(short8*)dst = o0;
        *(short8*)(dst + 8) = o1;
    } else {
        if (q4 == 0) { ml[w * 16 + ln] = m_i; ml[64 + w * 16 + ln] = l_i; }
        #pragma unroll
        for (int dt = 0; dt < 4; dt++) {
            uint2_t ow = {pkbf(OT[dt][0], OT[dt][1]),
                          pkbf(OT[dt][2], OT[dt][3])};
            *(uint2_t*)&Paw[ln * 136 + dt * 16 + q4 * 4] = ow;
        }
        short8 o0 = *(short8*)&Paw[ln * 136 + q4 * 16];
        short8 o1 = *(short8*)&Paw[ln * 136 + q4 * 16 + 8];
        short* Op = P_O + (size_t)p4 * 4096;
        *(short8*)&Op[(w * 16 + ln) * 64 + q4 * 16] = o0;
        *(short8*)&Op[(w * 16 + ln) * 64 + q4 * 16 + 8] = o1;
    }
    // gate softmax over lg for batch bi (2 blocks total do this)
    if (slot == 8 && qt == 0) {
        int b = bi;
        float v[8];
        float4 a0 = *(const float4*)&lg[b * N_SEQ + t * 8];
        float4 a1 = *(const float4*)&lg[b * N_SEQ + t * 8 + 4];
        v[0] = a0.x; v[1] = a0.y; v[2] = a0.z; v[3] = a0.w;
        v[4] = a1.x; v[5] = a1.y; v[6] = a1.z; v[7] = a1.w;
        float m = v[0];
        #pragma unroll
        for (int j = 1; j < 8; j++) m = fmaxf(m, v[j]);
        for (int o = 32; o; o >>= 1) m = fmaxf(m, __shfl_down(m, o));
        if ((t & 63) == 0) rg[t >> 6] = m;
        __syncthreads();
        m = fmaxf(fmaxf(rg[0], rg[1]), fmaxf(rg[2], rg[3]));
        float e[8], s = 0.f;
        #pragma unroll
        for (int j = 0; j < 8; j++) { e[j] = __expf(v[j] - m); s += e[j]; }
        for (int o = 32; o; o >>= 1) s += __shfl_down(s, o);
        if ((t & 63) == 0) rg[4 + (t >> 6)] = s;
        __syncthreads();
        s = (rg[4] + rg[5]) + (rg[6] + rg[7]);
        float inv = 1.f / s;
        float4 o0 = {e[0] * inv, e[1] * inv, e[2] * inv, e[3] * inv};
        float4 o1 = {e[4] * inv, e[5] * inv, e[6] * inv, e[7] * inv};
        *(float4*)&gate[b * N_SEQ + t * 8] = o0;
        *(float4*)&gate[b * N_SEQ + t * 8 + 4] = o1;
    }
}

// ---------------- combine partials -> obuf (multi-slot heads: h0, h1, h4) ------
// P_ml m-values are log2-domain; rescale with exp2f.
__global__ __launch_bounds__(256) void k_combine(const short* __restrict__ P_O,
                                                 const float* __restrict__ P_ml,
                                                 short* __restrict__ ob) {
    const int hsel[3]  = {0, 1, 4};
    const int hbase[3] = {0, 4, 10};
    const int hcnt[3]  = {4, 4, 2};
    int hh = blockIdx.x, qt = blockIdx.y, bi = blockIdx.z;
    int h = hsel[hh];
    int t = threadIdx.x;
    int row = t >> 2, c0 = (t & 3) * 16;
    int pb = (bi * 32 + qt) * NSLOT + hbase[hh];
    int cnt = hcnt[hh];
    float m = -1e30f;
    for (int s = 0; s < cnt; s++)
        m = fmaxf(m, P_ml[(size_t)(pb + s) * 128 + row]);
    float l = 0.f;
    float acc[16];
    #pragma unroll
    for (int j = 0; j < 16; j++) acc[j] = 0.f;
    for (int s = 0; s < cnt; s++) {
        float ms = P_ml[(size_t)(pb + s) * 128 + row];
        float ls = P_ml[(size_t)(pb + s) * 128 + 64 + row];
        if (ls > 0.f) {
            float sc = exp2f(ms - m);
            l += ls * sc;
            const short* Op = P_O + (size_t)(pb + s) * 4096 + row * 64 + c0;
            short8 v0 = *(const short8*)Op;
            short8 v1 = *(const short8*)(Op + 8);
            #pragma unroll
            for (int j = 0; j < 8; j++) acc[j]     += bf2f(v0[j]) * sc;
            #pragma unroll
            for (int j = 0; j < 8; j++) acc[8 + j] += bf2f(v1[j]) * sc;
        }
    }
    float inv = 1.f / l;
    int n = qt * 64 + row;
    short8 o0, o1;
    #pragma unroll
    for (int j = 0; j < 8; j++) o0[j] = f2bf(acc[j] * inv);
    #pragma unroll
    for (int j = 0; j < 8; j++) o1[j] = f2bf(acc[8 + j] * inv);
    short* dst = ob + ((size_t)bi * N_SEQ + n) * DM + h * 64 + c0;
    *(short8*)dst = o0;
    *(short8*)(dst + 8) = o1;
}

// ---------------- final: y = proj(bf16)*gate + x0 ; LN_out ----------------
__global__ __launch_bounds__(128) void k_final(const short* __restrict__ projb,
                                               const float* __restrict__ gate,
                                               const float* __restrict__ x0,
                                               const float* __restrict__ g,
                                               const float* __restrict__ b,
                                               float* __restrict__ out) {
    int tk = blockIdx.x, t = threadIdx.x;
    float gt = gate[tk];
    short4_t pv = *(const short4_t*)&projb[(size_t)tk * DM + t * 4];
    float4 xv = ((const float4*)(x0 + (size_t)tk * DM))[t];
    float4 y;
    y.x = bf2f(pv[0]) * gt + xv.x;
    y.y = bf2f(pv[1]) * gt + xv.y;
    y.z = bf2f(pv[2]) * gt + xv.z;
    y.w = bf2f(pv[3]) * gt + xv.w;
    float s = y.x + y.y + y.z + y.w;
    float q = y.x*y.x + y.y*y.y + y.z*y.z + y.w*y.w;
    for (int o = 32; o; o >>= 1) { s += __shfl_down(s, o); q += __shfl_down(q, o); }
    __shared__ float ls[2], lq[2];
    if ((t & 63) == 0) { ls[t >> 6] = s; lq[t >> 6] = q; }
    __syncthreads();
    s = ls[0] + ls[1]; q = lq[0] + lq[1];
    float mu = s * (1.f / DM);
    float var = q * (1.f / DM) - mu * mu;
    float rs = rsqrtf(var + 1e-5f);
    float4 gv = ((const float4*)g)[t], bv = ((const float4*)b)[t];
    float4 o;
    o.x = (y.x - mu) * rs * gv.x + bv.x;
    o.y = (y.y - mu) * rs * gv.y + bv.y;
    o.z = (y.z - mu) * rs * gv.z + bv.z;
    o.w = (y.w - mu) * rs * gv.w + bv.w;
    ((float4*)(out + (size_t)tk * DM))[t] = o;
}

extern "C" void kernel_launch(void* const* d_in, const int* in_sizes, int n_in,
                              void* d_out, int out_size, void* d_ws, size_t ws_size,
                              hipStream_t stream) {
    (void)in_sizes; (void)n_in; (void)out_size; (void)ws_size;
    const float* x    = (const float*)d_in[0];
    const float* Wq   = (const float*)d_in[1];
    const float* Wk   = (const float*)d_in[2];
    const float* Wv   = (const float*)d_in[3];
    const float* Wo   = (const float*)d_in[4];
    const float* Tw1  = (const float*)d_in[5];
    const float* Tb1  = (const float*)d_in[6];
    const float* Tw2  = (const float*)d_in[7];
    const float* ling = (const float*)d_in[9];
    const float* linb = (const float*)d_in[10];
    const float* logg = (const float*)d_in[11];
    const float* logb = (const float*)d_in[12];
    float* out = (float*)d_out;

    const size_t SZ = (size_t)NTOK * DM;
    const int NPART = 2 * 32 * NSLOT;  // 960 partial tiles
    char* p = (char*)d_ws;
    short* xn   = (short*)p; p += SZ * 2;
    short* wcat = (short*)p; p += (size_t)2048 * DM * 2;
    short* wo   = (short*)p; p += (size_t)DM * DM * 2;
    short* qb   = (short*)p; p += SZ * 2;
    short* kb   = (short*)p; p += SZ * 2;
    short* vtb  = (short*)p; p += SZ * 2;
    short* vb   = (short*)p; p += SZ * 2;
    short* obuf = (short*)p; p += SZ * 2;
    float* lg   = (float*)p; p += (size_t)NTOK * 4;
    float* gate = (float*)p; p += (size_t)NTOK * 4;
    float* P_ml = (float*)p; p += (size_t)NPART * 128 * 4;
    // projb (4 MB bf16) aliases P_O (7.9 MB): P_O dead after k_combine.
    short* projb = (short*)p;
    short* P_O   = (short*)p; p += (size_t)NPART * 4096 * 2;

    k_lncvt<<<3328, 256, 0, stream>>>(x, ling, linb, xn, lg,
                                      Wq, Wk, Wv, Tw1, Wo, wcat, wo);
    k_gemmqkvt<<<dim3(16, 32), 256, 0, stream>>>(xn, wcat, Tb1, Tw2,
                                                 qb, kb, vtb, vb, lg);
    k_attn<<<dim3(NSLOT, 32, 2), 256, 0, stream>>>(qb, kb, vtb, vb, P_O, P_ml,
                                                   obuf, lg, gate);
    k_combine<<<dim3(3, 32, 2), 256, 0, stream>>>(P_O, P_ml, obuf);
    k_gemmp<<<dim3(8, 32), 256, 0, stream>>>(obuf, wo, projb);
    k_final<<<NTOK, 128, 0, stream>>>(projb, gate, x, logg, logb, out);
}

// Round 11
// 145.595 us; speedup vs baseline: 1.0180x; 1.0180x over previous
//
#include <hip/hip_runtime.h>
#include <math.h>

#define N_SEQ 2048
#define DM    512
#define NTOK  4096
#define NH    8
#define HD    64
#define NSLOT 15

typedef __attribute__((ext_vector_type(8))) short short8;
typedef __attribute__((ext_vector_type(4))) short short4_t;
typedef __attribute__((ext_vector_type(4))) float f32x4;

__device__ inline short f2bf(float x) {
    union { float f; unsigned u; } v; v.f = x;
    unsigned r = v.u + 0x7fff + ((v.u >> 16) & 1);
    return (short)(r >> 16);
}
__device__ inline float bf2f(short s) {
    union { unsigned u; float f; } v; v.u = ((unsigned)(unsigned short)s) << 16;
    return v.f;
}
__device__ inline unsigned pkbf(float a, float b) {
    return ((unsigned)(unsigned short)f2bf(b) << 16) | (unsigned)(unsigned short)f2bf(a);
}
__device__ inline float ftanh(float x) {
    float e = __expf(2.f * x);
    return 1.f - 2.f / (e + 1.f);
}

__device__ inline f32x4 mfma16(short8 a, short8 b, f32x4 c) {
    return __builtin_amdgcn_mfma_f32_16x16x32_bf16(a, b, c, 0, 0, 0);
}

__device__ __forceinline__ void async_cp16(const short* g, short* l) {
    __builtin_amdgcn_global_load_lds(
        (const __attribute__((address_space(1))) void*)g,
        (__attribute__((address_space(3))) void*)l, 16, 0, 0);
}

// ---------------- fused: LN(x)->bf16 + lg zero-init  |  weight cvt fp32->bf16 ----
__global__ __launch_bounds__(256) void k_lncvt(
    const float* __restrict__ x, const float* __restrict__ g,
    const float* __restrict__ b, short* __restrict__ y, float* __restrict__ lg,
    const float* __restrict__ Wq, const float* __restrict__ Wk,
    const float* __restrict__ Wv, const float* __restrict__ Tw1,
    const float* __restrict__ Wo,
    short* __restrict__ wcat, short* __restrict__ wo) {
    int blk = blockIdx.x, t = threadIdx.x;
    if (blk < 2048) {
        int sub = t >> 7, tt = t & 127;
        int tk = blk * 2 + sub;
        if (tt == 0) lg[tk] = 0.f;
        float4 xv = ((const float4*)(x + (size_t)tk * DM))[tt];
        float s = xv.x + xv.y + xv.z + xv.w;
        float q = xv.x*xv.x + xv.y*xv.y + xv.z*xv.z + xv.w*xv.w;
        for (int o = 32; o; o >>= 1) { s += __shfl_down(s, o); q += __shfl_down(q, o); }
        __shared__ float ls[4], lq[4];
        if ((t & 63) == 0) { ls[t >> 6] = s; lq[t >> 6] = q; }
        __syncthreads();
        s = ls[sub * 2] + ls[sub * 2 + 1];
        q = lq[sub * 2] + lq[sub * 2 + 1];
        float mu = s * (1.f / DM);
        float var = q * (1.f / DM) - mu * mu;
        float rs = rsqrtf(var + 1e-5f);
        float4 gv = ((const float4*)g)[tt], bv = ((const float4*)b)[tt];
        short4_t o;
        o[0] = f2bf((xv.x - mu) * rs * gv.x + bv.x);
        o[1] = f2bf((xv.y - mu) * rs * gv.y + bv.y);
        o[2] = f2bf((xv.z - mu) * rs * gv.z + bv.z);
        o[3] = f2bf((xv.w - mu) * rs * gv.w + bv.w);
        *(short4_t*)&y[(size_t)tk * DM + tt * 4] = o;
    } else {
        int id = (blk - 2048) * 256 + t;
        if (id < 262144) {
            int z = id >> 16; int off = id & 65535;
            const float* s = (z == 0) ? Wq : (z == 1) ? Wk : (z == 2) ? Wv : Tw1;
            float4 v = ((const float4*)s)[off];
            short4_t o = {f2bf(v.x), f2bf(v.y), f2bf(v.z), f2bf(v.w)};
            *(short4_t*)(wcat + (size_t)z * 262144 + (size_t)off * 4) = o;
        } else {
            int off = id - 262144;
            float4 v = ((const float4*)Wo)[off];
            short4_t o = {f2bf(v.x), f2bf(v.y), f2bf(v.z), f2bf(v.w)};
            *(short4_t*)(wo + (size_t)off * 4) = o;
        }
    }
}

// ---------------- bf16 MFMA NT-GEMM (QKV + T-logit fused), BK=64 2-phase ------
// V epilogue: writes vtb ([b][h][d][n]); for dilated heads (5-7) also plain
// rows vb ([b][h][n][d]) used by compressed attention.
__global__ __launch_bounds__(256) void k_gemmqkvt(
    const short* __restrict__ A, const short* __restrict__ W,
    const float* __restrict__ Tb1, const float* __restrict__ Tw2,
    short* __restrict__ qb, short* __restrict__ kb, short* __restrict__ vtb,
    short* __restrict__ vb, float* __restrict__ lg) {
    __shared__ short smem[32768];   // max(2*(8192+8192), 128*136)
    int t = threadIdx.x;
    int lane = t & 63, w = t >> 6;
    int wy = w >> 1, wx = w & 1;
    int ln = lane & 15, q4 = lane >> 4;
    int c0 = blockIdx.x * 128, m0 = blockIdx.y * 128;
    f32x4 acc[4][4];
    f32x4 zero = {0.f, 0.f, 0.f, 0.f};
    #pragma unroll
    for (int i = 0; i < 4; i++)
        #pragma unroll
        for (int j = 0; j < 4; j++) acc[i][j] = zero;
    #pragma unroll
    for (int i2 = 0; i2 < 4; i2++) {
        int id = t + 256 * i2;
        int row = id >> 3, cc = id & 7;
        int scol = (cc ^ (row & 7)) << 3;
        async_cp16(&A[(size_t)(m0 + row) * DM + scol], &smem[id * 8]);
        async_cp16(&W[(size_t)(c0 + row) * DM + scol], &smem[8192 + id * 8]);
    }
    __syncthreads();
    for (int kk = 0; kk < 8; kk++) {
        short* AsB = &smem[(kk & 1) * 16384];
        short* BsB = AsB + 8192;
        if (kk < 7) {
            short* AsN = &smem[((kk & 1) ^ 1) * 16384];
            short* BsN = AsN + 8192;
            int k0 = (kk + 1) * 64;
            #pragma unroll
            for (int i2 = 0; i2 < 4; i2++) {
                int id = t + 256 * i2;
                int row = id >> 3, cc = id & 7;
                int scol = k0 + ((cc ^ (row & 7)) << 3);
                async_cp16(&A[(size_t)(m0 + row) * DM + scol], &AsN[id * 8]);
                async_cp16(&W[(size_t)(c0 + row) * DM + scol], &BsN[id * 8]);
            }
        }
        short8 af[2][4], bfr[2][4];
        #pragma unroll
        for (int ks = 0; ks < 2; ks++) {
            int chnk = ((ks * 4 + q4) ^ (ln & 7)) << 3;
            #pragma unroll
            for (int i = 0; i < 4; i++)
                af[ks][i] = *(short8*)&AsB[(wy * 64 + i * 16 + ln) * 64 + chnk];
            #pragma unroll
            for (int j = 0; j < 4; j++)
                bfr[ks][j] = *(short8*)&BsB[(wx * 64 + j * 16 + ln) * 64 + chnk];
        }
        #pragma unroll
        for (int ks = 0; ks < 2; ks++)
            #pragma unroll
            for (int i = 0; i < 4; i++)
                #pragma unroll
                for (int j = 0; j < 4; j++)
                    acc[i][j] = mfma16(af[ks][i], bfr[ks][j], acc[i][j]);
        __syncthreads();
    }
    short* Es = smem;
    int z = c0 >> 9;
    int bi = m0 >> 11, n0 = m0 & (N_SEQ - 1);
    int hp = (c0 & 511) >> 6;
    if (z < 2) {
        short* dst0 = (z == 0) ? qb : kb;
        float sc2 = (z == 0) ? 0.125f : 1.0f;
        #pragma unroll
        for (int i = 0; i < 4; i++)
            #pragma unroll
            for (int j = 0; j < 4; j++)
                #pragma unroll
                for (int r = 0; r < 4; r++) {
                    int nl = wy * 64 + i * 16 + q4 * 4 + r;
                    int cl = wx * 64 + j * 16 + ln;
                    Es[nl * 136 + cl] = f2bf(acc[i][j][r] * sc2);
                }
        __syncthreads();
        #pragma unroll
        for (int ii = 0; ii < 8; ii++) {
            int id = t + 256 * ii;
            int nl = id >> 4, c8 = id & 15;
            short8 v = *(short8*)&Es[nl * 136 + c8 * 8];
            int hh = hp + (c8 >> 3), d8 = (c8 & 7) * 8;
            *(short8*)&dst0[(((size_t)bi * NH + hh) * N_SEQ + n0 + nl) * HD + d8] = v;
        }
    } else if (z == 2) {
        if (hp >= 4) {
            // pass 1: plain rows -> vb for dilated heads (h >= 5)
            #pragma unroll
            for (int i = 0; i < 4; i++)
                #pragma unroll
                for (int j = 0; j < 4; j++)
                    #pragma unroll
                    for (int r = 0; r < 4; r++) {
                        int nl = wy * 64 + i * 16 + q4 * 4 + r;
                        int cl = wx * 64 + j * 16 + ln;
                        Es[nl * 136 + cl] = f2bf(acc[i][j][r]);
                    }
            __syncthreads();
            #pragma unroll
            for (int ii = 0; ii < 8; ii++) {
                int id = t + 256 * ii;
                int nl = id >> 4, c8 = id & 15;
                int hh = hp + (c8 >> 3);
                if (hh >= 5) {
                    short8 v = *(short8*)&Es[nl * 136 + c8 * 8];
                    int d8 = (c8 & 7) * 8;
                    *(short8*)&vb[(((size_t)bi * NH + hh) * N_SEQ + n0 + nl) * HD + d8] = v;
                }
            }
            __syncthreads();
        }
        // pass 2: transposed [d_local][n_local] -> vtb
        #pragma unroll
        for (int i = 0; i < 4; i++)
            #pragma unroll
            for (int j = 0; j < 4; j++) {
                int nl0 = wy * 64 + i * 16 + q4 * 4;
                int dl = wx * 64 + j * 16 + ln;
                *(unsigned*)&Es[dl * 136 + nl0]     = pkbf(acc[i][j][0], acc[i][j][1]);
                *(unsigned*)&Es[dl * 136 + nl0 + 2] = pkbf(acc[i][j][2], acc[i][j][3]);
            }
        __syncthreads();
        #pragma unroll
        for (int ii = 0; ii < 8; ii++) {
            int id = t + 256 * ii;
            int dl = id >> 4, nc = id & 15;
            short8 v = *(short8*)&Es[dl * 136 + nc * 8];
            int h = hp + (dl >> 6), d = dl & 63;
            *(short8*)&vtb[(((size_t)bi * NH + h) * HD + d) * N_SEQ + n0 + nc * 8] = v;
        }
    } else {
        #pragma unroll
        for (int i = 0; i < 4; i++) {
            #pragma unroll
            for (int r = 0; r < 4; r++) {
                float s = 0.f;
                #pragma unroll
                for (int j = 0; j < 4; j++) {
                    int tc = (c0 & 511) + wx * 64 + j * 16 + ln;
                    s += ftanh(acc[i][j][r] + Tb1[tc]) * Tw2[tc];
                }
                s += __shfl_xor(s, 1);
                s += __shfl_xor(s, 2);
                s += __shfl_xor(s, 4);
                s += __shfl_xor(s, 8);
                if (ln == 0) {
                    int row = m0 + wy * 64 + i * 16 + q4 * 4 + r;
                    atomicAdd(&lg[row], s);
                }
            }
        }
    }
}

// ---------------- proj GEMM 128x64 tiles, BK=64 2-phase: proj(bf16) = A @ Wo^T --
__global__ __launch_bounds__(256) void k_gemmp(
    const short* __restrict__ A, const short* __restrict__ W,
    short* __restrict__ projb) {
    __shared__ short smem[24576];
    int t = threadIdx.x;
    int lane = t & 63, w = t >> 6;
    int wy = w >> 1, wx = w & 1;
    int ln = lane & 15, q4 = lane >> 4;
    int c0 = blockIdx.x * 64, m0 = blockIdx.y * 128;
    f32x4 acc[4][2];
    f32x4 zero = {0.f, 0.f, 0.f, 0.f};
    #pragma unroll
    for (int i = 0; i < 4; i++) { acc[i][0] = zero; acc[i][1] = zero; }
    #pragma unroll
    for (int i2 = 0; i2 < 4; i2++) {
        int id = t + 256 * i2;
        int row = id >> 3, cc = id & 7;
        int scol = (cc ^ (row & 7)) << 3;
        async_cp16(&A[(size_t)(m0 + row) * DM + scol], &smem[id * 8]);
        if (i2 < 2)
            async_cp16(&W[(size_t)(c0 + row) * DM + scol], &smem[8192 + id * 8]);
    }
    __syncthreads();
    for (int kk = 0; kk < 8; kk++) {
        short* AsB = &smem[(kk & 1) * 12288];
        short* BsB = AsB + 8192;
        if (kk < 7) {
            short* AsN = &smem[((kk & 1) ^ 1) * 12288];
            short* BsN = AsN + 8192;
            int k0 = (kk + 1) * 64;
            #pragma unroll
            for (int i2 = 0; i2 < 4; i2++) {
                int id = t + 256 * i2;
                int row = id >> 3, cc = id & 7;
                int scol = k0 + ((cc ^ (row & 7)) << 3);
                async_cp16(&A[(size_t)(m0 + row) * DM + scol], &AsN[id * 8]);
                if (i2 < 2)
                    async_cp16(&W[(size_t)(c0 + row) * DM + scol], &BsN[id * 8]);
            }
        }
        short8 af[2][4], bfr[2][2];
        #pragma unroll
        for (int ks = 0; ks < 2; ks++) {
            int chnk = ((ks * 4 + q4) ^ (ln & 7)) << 3;
            #pragma unroll
            for (int i = 0; i < 4; i++)
                af[ks][i] = *(short8*)&AsB[(wy * 64 + i * 16 + ln) * 64 + chnk];
            #pragma unroll
            for (int j = 0; j < 2; j++)
                bfr[ks][j] = *(short8*)&BsB[(wx * 32 + j * 16 + ln) * 64 + chnk];
        }
        #pragma unroll
        for (int ks = 0; ks < 2; ks++)
            #pragma unroll
            for (int i = 0; i < 4; i++)
                #pragma unroll
                for (int j = 0; j < 2; j++)
                    acc[i][j] = mfma16(af[ks][i], bfr[ks][j], acc[i][j]);
        __syncthreads();
    }
    short* Es = smem;
    #pragma unroll
    for (int i = 0; i < 4; i++)
        #pragma unroll
        for (int j = 0; j < 2; j++)
            #pragma unroll
            for (int r = 0; r < 4; r++) {
                int nl = wy * 64 + i * 16 + q4 * 4 + r;
                int cl = wx * 32 + j * 16 + ln;
                Es[nl * 72 + cl] = f2bf(acc[i][j][r]);
            }
    __syncthreads();
    #pragma unroll
    for (int ii = 0; ii < 4; ii++) {
        int id = t + 256 * ii;
        int nl = id >> 3, c8 = id & 7;
        short8 v = *(short8*)&Es[nl * 72 + c8 * 8];
        *(short8*)&projb[(size_t)(m0 + nl) * DM + c0 + c8 * 8] = v;
    }
}

// ---------------- split-K MFMA flash attention, 128-key tiles ----------------
// Slots (NSLOT=15): h0:0-3 h1:4-7 h2:8 h3:9 h4:10-11 h5:12 h6:13 h7:14.
// Dilated heads (5-7) run in RESIDUE-COMPRESSED coordinates: query block = 64
// same-residue queries, keys gathered with stride d, mask = window-64 in
// compressed space. K gathered from kb rows; V gathered as rows from vb and
// transposed in-place in LDS into the standard swizzled Vt layout. These heads
// need <=2 key tiles -> solo (direct obuf write).
__global__ __launch_bounds__(256) void k_attn(const short* __restrict__ qb,
                                              const short* __restrict__ kb,
                                              const short* __restrict__ vtb,
                                              const short* __restrict__ vb,
                                              short* __restrict__ P_O,
                                              float* __restrict__ P_ml,
                                              short* __restrict__ ob,
                                              const float* __restrict__ lg,
                                              float* __restrict__ gate) {
    __shared__ short Ks[128 * 64];      // linear [key][d], content chunk-swizzled
    __shared__ short Vt[64 * 128];      // [d][key] swizzled; dilated: first V-row staging [128][64]
    __shared__ short Pa[4][16 * 136];   // per-wave [qrow][key] pad136
    __shared__ float rg[8];
    int t = threadIdx.x;
    int lane = t & 63, w = t >> 6;
    int ln = lane & 15, q4 = lane >> 4;
    int slot = blockIdx.x, qt = blockIdx.y, bi = blockIdx.z;
    int h, c;
    if (slot < 4)        { h = 0; c = slot; }
    else if (slot < 8)   { h = 1; c = slot - 4; }
    else if (slot == 8)  { h = 2; c = 0; }
    else if (slot == 9)  { h = 3; c = 0; }
    else if (slot < 12)  { h = 4; c = slot - 10; }
    else                 { h = slot - 7; c = 0; }      // 12,13,14 -> h5,h6,h7
    int solo = (slot == 8) | (slot == 9) | (slot >= 12);
    int kind = (h < 2) ? 0 : (h < 5) ? 1 : 2;
    int wnd = (h == 2 || h >= 5) ? 64 : (h == 3) ? 128 : 256;
    int dsh = (h >= 5) ? (h - 4) : 0;                  // dilation shift: h5->1 h6->2 h7->3
    int ktLo, ktHi, q0m, rres = 0;
    if (kind == 0) {
        q0m = qt * 64; ktLo = c * 4; ktHi = ktLo + 3;
    } else if (kind == 1) {
        q0m = qt * 64;
        int tLoU = (q0m - wnd) >> 7, tHiU = (q0m + 63 + wnd) >> 7;
        ktLo = tLoU + c * 3; ktHi = ktLo + 2;
        if (ktHi > tHiU) ktHi = tHiU;
        if (ktHi > 15) ktHi = 15;
        if (ktLo < 0) ktLo = 0;
    } else {
        int nct = 32 >> dsh;                 // query tiles per residue
        rres = qt >> (5 - dsh);              // residue class
        q0m = (qt & (nct - 1)) * 64;         // compressed query base
        int Lt = 16 >> dsh;                  // compressed key tiles
        ktLo = (q0m - 64) >> 7; if (ktLo < 0) ktLo = 0;
        ktHi = (q0m + 127) >> 7; if (ktHi > Lt - 1) ktHi = Lt - 1;
    }
    int p4 = (bi * 32 + qt) * NSLOT + slot;
    float* ml = P_ml + (size_t)p4 * 128;
    if (ktLo > ktHi) {
        if (t < 64) { ml[t] = -1e30f; ml[64 + t] = 0.f; }
        return;
    }
    const size_t base = ((size_t)bi * NH + h) * N_SEQ * HD;
    const short* Q = qb + base;
    const short* K = kb + base;
    const short* Vg = vtb + base;   // [d][n]
    const short* Vr = vb + base;    // [n][d] (dilated heads only)
    int qm = q0m + w * 16 + ln;                         // mask-space coordinate
    int qi = (kind == 2) ? (rres + (qm << dsh)) : qm;   // physical query row
    short8 qa[2];
    {
        const short* qrow = Q + (size_t)qi * HD + q4 * 8;
        qa[0] = *(const short8*)qrow;
        qa[1] = *(const short8*)(qrow + 32);
    }
    float m_i = -1e30f, l_i = 0.f;
    f32x4 OT[4];
    f32x4 zero = {0.f, 0.f, 0.f, 0.f};
    #pragma unroll
    for (int d = 0; d < 4; d++) OT[d] = zero;
    short* Paw = Pa[w];
    for (int kt = ktLo; kt <= ktHi; kt++) {
        int k0 = kt << 7;
        __syncthreads();
        if (kind != 2) {
            #pragma unroll
            for (int i2 = 0; i2 < 4; i2++) {
                int id = t + 256 * i2;
                int kr = id >> 3, ck = id & 7;
                async_cp16(&K[(size_t)(k0 + kr) * HD + ((ck ^ (kr & 7)) << 3)],
                           &Ks[id << 3]);
                int dr = id >> 4, cv = id & 15;
                async_cp16(&Vg[(size_t)dr * N_SEQ + k0 + ((cv ^ (dr & 15)) << 3)],
                           &Vt[id << 3]);
            }
        } else {
            // compressed gather: row kr -> physical key rres + (k0+kr)*d
            #pragma unroll
            for (int i2 = 0; i2 < 4; i2++) {
                int id = t + 256 * i2;
                int kr = id >> 3, ck = id & 7;
                int kn = rres + ((k0 + kr) << dsh);
                async_cp16(&K[(size_t)kn * HD + ((ck ^ (kr & 7)) << 3)],
                           &Ks[id << 3]);
                async_cp16(&Vr[(size_t)kn * HD + (ck << 3)],
                           &Vt[id << 3]);    // V rows staged linear [128][64]
            }
        }
        __syncthreads();
        // S^T = K·Q^T over 128 keys
        f32x4 ST[8];
        #pragma unroll
        for (int nt = 0; nt < 8; nt++) ST[nt] = zero;
        __builtin_amdgcn_s_setprio(1);
        #pragma unroll
        for (int nt = 0; nt < 8; nt++) {
            #pragma unroll
            for (int ks = 0; ks < 2; ks++) {
                int cc = ((ks * 4 + q4) ^ (ln & 7)) << 3;
                short8 af = *(short8*)&Ks[(nt * 16 + ln) * 64 + cc];
                ST[nt] = mfma16(af, qa[ks], ST[nt]);
            }
        }
        __builtin_amdgcn_s_setprio(0);
        if (kind != 0) {
            // window mask in (compressed or plain) coordinates
            #pragma unroll
            for (int nt = 0; nt < 8; nt++)
                #pragma unroll
                for (int r = 0; r < 4; r++) {
                    int key = k0 + nt * 16 + q4 * 4 + r;
                    int dlt = qm - key; dlt = (dlt < 0) ? -dlt : dlt;
                    if (dlt > wnd) ST[nt][r] = -1e30f;
                }
        }
        float rm = -1e30f;
        #pragma unroll
        for (int nt = 0; nt < 8; nt++) {
            float a = fmaxf(ST[nt][0], ST[nt][1]);
            float b = fmaxf(ST[nt][2], ST[nt][3]);
            rm = fmaxf(rm, fmaxf(a, b));
        }
        rm = fmaxf(rm, __shfl_xor(rm, 16));
        rm = fmaxf(rm, __shfl_xor(rm, 32));
        float mn = fmaxf(m_i, rm);
        float sc = __expf(m_i - mn);
        float rs = 0.f;
        #pragma unroll
        for (int nt = 0; nt < 8; nt++) {
            float p0 = __expf(ST[nt][0] - mn);
            float p1 = __expf(ST[nt][1] - mn);
            float p2 = __expf(ST[nt][2] - mn);
            float p3 = __expf(ST[nt][3] - mn);
            rs += (p0 + p1) + (p2 + p3);
            *(unsigned*)&Paw[ln * 136 + nt * 16 + q4 * 4]     = pkbf(p0, p1);
            *(unsigned*)&Paw[ln * 136 + nt * 16 + q4 * 4 + 2] = pkbf(p2, p3);
        }
        rs += __shfl_xor(rs, 16);
        rs += __shfl_xor(rs, 32);
        l_i = l_i * sc + rs;
        m_i = mn;
        #pragma unroll
        for (int d = 0; d < 4; d++) OT[d] *= sc;
        if (kind == 2) {
            // in-place LDS transpose: Vrow[128][64] -> Vt[64][128] (swizzled)
            int dr = t & 63, cb = t >> 6;
            short8 tv[4];
            #pragma unroll
            for (int e = 0; e < 4; e++) {
                int c8 = cb + e * 4;
                #pragma unroll
                for (int j = 0; j < 8; j++)
                    tv[e][j] = Vt[(c8 * 8 + j) * 64 + dr];
            }
            __syncthreads();
            #pragma unroll
            for (int e = 0; e < 4; e++) {
                int c8 = cb + e * 4;
                *(short8*)&Vt[dr * 128 + ((c8 ^ (dr & 15)) << 3)] = tv[e];
            }
            __syncthreads();
        }
        // O^T += V^T · P^T
        short8 pb[4];
        #pragma unroll
        for (int ks = 0; ks < 4; ks++)
            pb[ks] = *(short8*)&Paw[ln * 136 + ks * 32 + q4 * 8];
        __builtin_amdgcn_s_setprio(1);
        #pragma unroll
        for (int dt = 0; dt < 4; dt++) {
            #pragma unroll
            for (int ks = 0; ks < 4; ks++) {
                int cc = ((ks * 4 + q4) ^ ln) << 3;
                short8 a = *(short8*)&Vt[(dt * 16 + ln) * 128 + cc];
                OT[dt] = mfma16(a, pb[ks], OT[dt]);
            }
        }
        __builtin_amdgcn_s_setprio(0);
    }
    if (solo) {
        float inv = 1.f / l_i;
        #pragma unroll
        for (int dt = 0; dt < 4; dt++) {
            *(unsigned*)&Paw[ln * 136 + dt * 16 + q4 * 4]     = pkbf(OT[dt][0] * inv, OT[dt][1] * inv);
            *(unsigned*)&Paw[ln * 136 + dt * 16 + q4 * 4 + 2] = pkbf(OT[dt][2] * inv, OT[dt][3] * inv);
        }
        short8 o0 = *(short8*)&Paw[ln * 136 + q4 * 16];
        short8 o1 = *(short8*)&Paw[ln * 136 + q4 * 16 + 8];
        short* dst = ob + ((size_t)bi * N_SEQ + qi) * DM + h * 64 + q4 * 16;
        *(short8*)dst = o0;
        *(short8*)(dst + 8) = o1;
    } else {
        if (q4 == 0) { ml[w * 16 + ln] = m_i; ml[64 + w * 16 + ln] = l_i; }
        #pragma unroll
        for (int dt = 0; dt < 4; dt++) {
            *(unsigned*)&Paw[ln * 136 + dt * 16 + q4 * 4]     = pkbf(OT[dt][0], OT[dt][1]);
            *(unsigned*)&Paw[ln * 136 + dt * 16 + q4 * 4 + 2] = pkbf(OT[dt][2], OT[dt][3]);
        }
        short8 o0 = *(short8*)&Paw[ln * 136 + q4 * 16];
        short8 o1 = *(short8*)&Paw[ln * 136 + q4 * 16 + 8];
        short* Op = P_O + (size_t)p4 * 4096;
        *(short8*)&Op[(w * 16 + ln) * 64 + q4 * 16] = o0;
        *(short8*)&Op[(w * 16 + ln) * 64 + q4 * 16 + 8] = o1;
    }
    // gate softmax over lg for batch bi (2 blocks total do this)
    if (slot == 8 && qt == 0) {
        int b = bi;
        float v[8];
        float4 a0 = *(const float4*)&lg[b * N_SEQ + t * 8];
        float4 a1 = *(const float4*)&lg[b * N_SEQ + t * 8 + 4];
        v[0] = a0.x; v[1] = a0.y; v[2] = a0.z; v[3] = a0.w;
        v[4] = a1.x; v[5] = a1.y; v[6] = a1.z; v[7] = a1.w;
        float m = v[0];
        #pragma unroll
        for (int j = 1; j < 8; j++) m = fmaxf(m, v[j]);
        for (int o = 32; o; o >>= 1) m = fmaxf(m, __shfl_down(m, o));
        if ((t & 63) == 0) rg[t >> 6] = m;
        __syncthreads();
        m = fmaxf(fmaxf(rg[0], rg[1]), fmaxf(rg[2], rg[3]));
        float e[8], s = 0.f;
        #pragma unroll
        for (int j = 0; j < 8; j++) { e[j] = __expf(v[j] - m); s += e[j]; }
        for (int o = 32; o; o >>= 1) s += __shfl_down(s, o);
        if ((t & 63) == 0) rg[4 + (t >> 6)] = s;
        __syncthreads();
        s = (rg[4] + rg[5]) + (rg[6] + rg[7]);
        float inv = 1.f / s;
        float4 o0 = {e[0] * inv, e[1] * inv, e[2] * inv, e[3] * inv};
        float4 o1 = {e[4] * inv, e[5] * inv, e[6] * inv, e[7] * inv};
        *(float4*)&gate[b * N_SEQ + t * 8] = o0;
        *(float4*)&gate[b * N_SEQ + t * 8 + 4] = o1;
    }
}

// ---------------- combine partials -> obuf (multi-slot heads: h0, h1, h4) ------
__global__ __launch_bounds__(256) void k_combine(const short* __restrict__ P_O,
                                                 const float* __restrict__ P_ml,
                                                 short* __restrict__ ob) {
    const int hsel[3]  = {0, 1, 4};
    const int hbase[3] = {0, 4, 10};
    const int hcnt[3]  = {4, 4, 2};
    int hh = blockIdx.x, qt = blockIdx.y, bi = blockIdx.z;
    int h = hsel[hh];
    int t = threadIdx.x;
    int row = t >> 2, c0 = (t & 3) * 16;
    int pb = (bi * 32 + qt) * NSLOT + hbase[hh];
    int cnt = hcnt[hh];
    float m = -1e30f;
    for (int s = 0; s < cnt; s++)
        m = fmaxf(m, P_ml[(size_t)(pb + s) * 128 + row]);
    float l = 0.f;
    float acc[16];
    #pragma unroll
    for (int j = 0; j < 16; j++) acc[j] = 0.f;
    for (int s = 0; s < cnt; s++) {
        float ms = P_ml[(size_t)(pb + s) * 128 + row];
        float ls = P_ml[(size_t)(pb + s) * 128 + 64 + row];
        if (ls > 0.f) {
            float sc = __expf(ms - m);
            l += ls * sc;
            const short* Op = P_O + (size_t)(pb + s) * 4096 + row * 64 + c0;
            short8 v0 = *(const short8*)Op;
            short8 v1 = *(const short8*)(Op + 8);
            #pragma unroll
            for (int j = 0; j < 8; j++) acc[j]     += bf2f(v0[j]) * sc;
            #pragma unroll
            for (int j = 0; j < 8; j++) acc[8 + j] += bf2f(v1[j]) * sc;
        }
    }
    float inv = 1.f / l;
    int n = qt * 64 + row;
    short8 o0, o1;
    #pragma unroll
    for (int j = 0; j < 8; j++) o0[j] = f2bf(acc[j] * inv);
    #pragma unroll
    for (int j = 0; j < 8; j++) o1[j] = f2bf(acc[8 + j] * inv);
    short* dst = ob + ((size_t)bi * N_SEQ + n) * DM + h * 64 + c0;
    *(short8*)dst = o0;
    *(short8*)(dst + 8) = o1;
}

// ---------------- final: y = proj(bf16)*gate + x0 ; LN_out ----------------
__global__ __launch_bounds__(128) void k_final(const short* __restrict__ projb,
                                               const float* __restrict__ gate,
                                               const float* __restrict__ x0,
                                               const float* __restrict__ g,
                                               const float* __restrict__ b,
                                               float* __restrict__ out) {
    int tk = blockIdx.x, t = threadIdx.x;
    float gt = gate[tk];
    short4_t pv = *(const short4_t*)&projb[(size_t)tk * DM + t * 4];
    float4 xv = ((const float4*)(x0 + (size_t)tk * DM))[t];
    float4 y;
    y.x = bf2f(pv[0]) * gt + xv.x;
    y.y = bf2f(pv[1]) * gt + xv.y;
    y.z = bf2f(pv[2]) * gt + xv.z;
    y.w = bf2f(pv[3]) * gt + xv.w;
    float s = y.x + y.y + y.z + y.w;
    float q = y.x*y.x + y.y*y.y + y.z*y.z + y.w*y.w;
    for (int o = 32; o; o >>= 1) { s += __shfl_down(s, o); q += __shfl_down(q, o); }
    __shared__ float ls[2], lq[2];
    if ((t & 63) == 0) { ls[t >> 6] = s; lq[t >> 6] = q; }
    __syncthreads();
    s = ls[0] + ls[1]; q = lq[0] + lq[1];
    float mu = s * (1.f / DM);
    float var = q * (1.f / DM) - mu * mu;
    float rs = rsqrtf(var + 1e-5f);
    float4 gv = ((const float4*)g)[t], bv = ((const float4*)b)[t];
    float4 o;
    o.x = (y.x - mu) * rs * gv.x + bv.x;
    o.y = (y.y - mu) * rs * gv.y + bv.y;
    o.z = (y.z - mu) * rs * gv.z + bv.z;
    o.w = (y.w - mu) * rs * gv.w + bv.w;
    ((float4*)(out + (size_t)tk * DM))[t] = o;
}

extern "C" void kernel_launch(void* const* d_in, const int* in_sizes, int n_in,
                              void* d_out, int out_size, void* d_ws, size_t ws_size,
                              hipStream_t stream) {
    (void)in_sizes; (void)n_in; (void)out_size; (void)ws_size;
    const float* x    = (const float*)d_in[0];
    const float* Wq   = (const float*)d_in[1];
    const float* Wk   = (const float*)d_in[2];
    const float* Wv   = (const float*)d_in[3];
    const float* Wo   = (const float*)d_in[4];
    const float* Tw1  = (const float*)d_in[5];
    const float* Tb1  = (const float*)d_in[6];
    const float* Tw2  = (const float*)d_in[7];
    const float* ling = (const float*)d_in[9];
    const float* linb = (const float*)d_in[10];
    const float* logg = (const float*)d_in[11];
    const float* logb = (const float*)d_in[12];
    float* out = (float*)d_out;

    const size_t SZ = (size_t)NTOK * DM;
    const int NPART = 2 * 32 * NSLOT;  // 960 partial tiles
    char* p = (char*)d_ws;
    short* xn   = (short*)p; p += SZ * 2;
    short* wcat = (short*)p; p += (size_t)2048 * DM * 2;
    short* wo   = (short*)p; p += (size_t)DM * DM * 2;
    short* qb   = (short*)p; p += SZ * 2;
    short* kb   = (short*)p; p += SZ * 2;
    short* vtb  = (short*)p; p += SZ * 2;
    short* vb   = (short*)p; p += SZ * 2;
    short* obuf = (short*)p; p += SZ * 2;
    float* lg   = (float*)p; p += (size_t)NTOK * 4;
    float* gate = (float*)p; p += (size_t)NTOK * 4;
    float* P_ml = (float*)p; p += (size_t)NPART * 128 * 4;
    // projb (4 MB bf16) aliases P_O (7.9 MB): P_O dead after k_combine.
    short* projb = (short*)p;
    short* P_O   = (short*)p; p += (size_t)NPART * 4096 * 2;

    k_lncvt<<<3328, 256, 0, stream>>>(x, ling, linb, xn, lg,
                                      Wq, Wk, Wv, Tw1, Wo, wcat, wo);
    k_gemmqkvt<<<dim3(16, 32), 256, 0, stream>>>(xn, wcat, Tb1, Tw2,
                                                 qb, kb, vtb, vb, lg);
    k_attn<<<dim3(NSLOT, 32, 2), 256, 0, stream>>>(qb, kb, vtb, vb, P_O, P_ml,
                                                   obuf, lg, gate);
    k_combine<<<dim3(3, 32, 2), 256, 0, stream>>>(P_O, P_ml, obuf);
    k_gemmp<<<dim3(8, 32), 256, 0, stream>>>(obuf, wo, projb);
    k_final<<<NTOK, 128, 0, stream>>>(projb, gate, x, logg, logb, out);
}